// Round 3
// baseline (882.154 us; speedup 1.0000x reference)
//
#include <hip/hip_runtime.h>
#include <hip/hip_bf16.h>
#include <math.h>

// EncoderBlock: B=2, S=4096, D_MODEL=768, H=12, dk=64, D_FF=3072.
// Inputs fp32 (mask int32), output fp32. Internal compute bf16 MFMA.

typedef __hip_bfloat16 bf16;
typedef short short8 __attribute__((ext_vector_type(8)));   // 8 bf16 (4 VGPRs)
typedef short short4v __attribute__((ext_vector_type(4)));  // 4 bf16 (8B)
typedef float f32x4 __attribute__((ext_vector_type(4)));

#define MFMA(A, B, C) __builtin_amdgcn_mfma_f32_16x16x32_bf16(A, B, C, 0, 0, 0)

__device__ __forceinline__ short f2b(float f) {
  bf16 h = __float2bfloat16(f);
  return *reinterpret_cast<short*>(&h);
}
__device__ __forceinline__ float b2f(const bf16& h) { return __bfloat162float(h); }

// ---------------- fp32 -> bf16 conversion (vectorized x4) -------------------
__global__ __launch_bounds__(256)
void conv_kernel(const float* __restrict__ src, bf16* __restrict__ dst, int n4)
{
  const int i = blockIdx.x * 256 + threadIdx.x;
  if (i < n4) {
    float4 v = ((const float4*)src)[i];
    short4v o;
    o.x = f2b(v.x); o.y = f2b(v.y); o.z = f2b(v.z); o.w = f2b(v.w);
    ((short4v*)dst)[i] = o;
  }
}

// ---------------- LayerNorm (scalar alpha/beta, unbiased std) ----------------
template<typename INT>
__global__ __launch_bounds__(256)
void ln_kernel(const INT* __restrict__ x, bf16* __restrict__ out,
               const float* __restrict__ alpha, const float* __restrict__ beta)
{
  const int row = blockIdx.x;
  const long base = (long)row * 768;
  const int t = threadIdx.x;
  float v[3]; float s = 0.f, ss = 0.f;
#pragma unroll
  for (int i = 0; i < 3; i++) {
    v[i] = (float)x[base + t + i * 256];
    s += v[i]; ss += v[i] * v[i];
  }
#pragma unroll
  for (int off = 32; off > 0; off >>= 1) {
    s  += __shfl_down(s, off);
    ss += __shfl_down(ss, off);
  }
  __shared__ float red[8];
  __shared__ float stats[2];
  const int w = t >> 6;
  if ((t & 63) == 0) { red[w] = s; red[4 + w] = ss; }
  __syncthreads();
  if (t == 0) {
    float S  = red[0] + red[1] + red[2] + red[3];
    float SS = red[4] + red[5] + red[6] + red[7];
    float mean = S * (1.f / 768.f);
    float var = fmaxf((SS - 768.f * mean * mean) * (1.f / 767.f), 0.f);
    stats[0] = mean;
    stats[1] = 1.f / (sqrtf(var) + 1e-6f);   // 1/(std+eps)
  }
  __syncthreads();
  const float mean = stats[0], rinv = stats[1];
  const float a = alpha[0], b = beta[0];
#pragma unroll
  for (int i = 0; i < 3; i++)
    out[base + t + i * 256] = __float2bfloat16(a * (v[i] - mean) * rinv + b);
}

// ---------------- GEMM: C[m][n] = sum_k A[m][k]*W[n][k] + bias[n] ------------
// MODE: 0 plain | 1 +ReLU | 2 scatter [B,H,S,dk] | 3 scatter [B,H,dk,S] (V^T)
//       4 +residual R[m][n]
template<int MODE, typename RT, typename OUTT>
__global__ __launch_bounds__(256)
void gemm_bt(const bf16* __restrict__ A, const bf16* __restrict__ W,
             const float* __restrict__ bias, const RT* __restrict__ R,
             OUTT* __restrict__ Cout, int M, int N, int K)
{
  __shared__ __align__(16) bf16 sA[128 * 32];
  __shared__ __align__(16) bf16 sB[128 * 32];
  const int t = threadIdx.x;
  const int w = t >> 6, lane = t & 63;
  const int lr = lane & 15, quad = lane >> 4;
  const int tm = blockIdx.x * 128, tn = blockIdx.y * 128;
  const int wm = (w >> 1) * 64, wn = (w & 1) * 64;

  const int srow = w * 16 + (lane >> 2);
  const int scol = (lane & 3) * 8;
  const bf16* Ap = A + (long)(tm + srow) * K + scol;
  const bf16* Wp = W + (long)(tn + srow) * K + scol;
  bf16* sAp = &sA[srow * 32 + scol];
  bf16* sBp = &sB[srow * 32 + scol];
  const long half = (long)64 * K;

  f32x4 acc[4][4] = {};

  for (int kb = 0; kb < K; kb += 32) {
    short8 va0 = *(const short8*)(Ap + kb);
    short8 va1 = *(const short8*)(Ap + kb + half);
    short8 vb0 = *(const short8*)(Wp + kb);
    short8 vb1 = *(const short8*)(Wp + kb + half);
    *(short8*)sAp            = va0;
    *(short8*)(sAp + 64*32)  = va1;
    *(short8*)sBp            = vb0;
    *(short8*)(sBp + 64*32)  = vb1;
    __syncthreads();
    short8 af[4], bfr[4];
#pragma unroll
    for (int i = 0; i < 4; i++)
      af[i] = *(const short8*)&sA[(wm + i * 16 + lr) * 32 + quad * 8];
#pragma unroll
    for (int j = 0; j < 4; j++)
      bfr[j] = *(const short8*)&sB[(wn + j * 16 + lr) * 32 + quad * 8];
#pragma unroll
    for (int i = 0; i < 4; i++)
#pragma unroll
      for (int j = 0; j < 4; j++)
        acc[i][j] = MFMA(af[i], bfr[j], acc[i][j]);
    __syncthreads();
  }

#pragma unroll
  for (int i = 0; i < 4; i++) {
#pragma unroll
    for (int j = 0; j < 4; j++) {
      const int col = tn + wn + j * 16 + lr;
      const float bv = bias[col];
#pragma unroll
      for (int r = 0; r < 4; r++) {
        const int m = tm + wm + i * 16 + quad * 4 + r;
        float vv = acc[i][j][r] + bv;
        if (MODE == 1) vv = fmaxf(vv, 0.f);
        if (MODE == 4) vv += (float)R[(long)m * N + col];
        long oidx;
        if (MODE == 2) {
          const int hh = col >> 6, d = col & 63, bb = m >> 12, sdx = m & 4095;
          oidx = ((long)(bb * 12 + hh) * 4096 + sdx) * 64 + d;
        } else if (MODE == 3) {
          const int hh = col >> 6, d = col & 63, bb = m >> 12, sdx = m & 4095;
          oidx = ((long)(bb * 12 + hh) * 64 + d) * 4096 + sdx;
        } else {
          oidx = (long)m * N + col;
        }
        Cout[oidx] = (OUTT)vv;   // bf16: RNE convert; float: exact
      }
    }
  }
}

// ---------------- Flash attention: block = (qtile of 64) x (b,h) -------------
// Q,K: [B,H,S,64]; Vt: [B,H,64,S]; ctx out: [B,S,768] (all bf16)
__global__ __launch_bounds__(256)
void attn_kernel(const bf16* __restrict__ Q, const bf16* __restrict__ Kg,
                 const bf16* __restrict__ Vt, const int* __restrict__ mask,
                 bf16* __restrict__ ctx)
{
  __shared__ __align__(16) bf16 sK[32 * 64];   // [key][d]
  __shared__ __align__(16) bf16 sV[64 * 32];   // [d][key]
  __shared__ __align__(16) bf16 sP[4][16 * 32];// per-wave P tile [q][key]
  __shared__ float sBias[4096];

  const int t = threadIdx.x, w = t >> 6, lane = t & 63;
  const int lr = lane & 15, quad = lane >> 4;
  const int bh = blockIdx.y;
  const int b = bh / 12, hh = bh % 12;
  const int qb = blockIdx.x * 64 + w * 16;     // this wave's 16 queries
  const long bh_s = (long)bh * 4096;

  for (int i = t; i < 4096; i += 256)
    sBias[i] = mask[b * 4096 + i] ? 0.f : -1e9f;

  const bf16* qp = Q + (bh_s + qb + lr) * 64 + quad * 8;
  short8 q0 = *(const short8*)qp;
  short8 q1 = *(const short8*)(qp + 32);

  float m_i[4], l_i[4];
  f32x4 O[4] = {};
#pragma unroll
  for (int r = 0; r < 4; r++) { m_i[r] = -INFINITY; l_i[r] = 0.f; }

  const bf16* kp = Kg + (bh_s + (t >> 3)) * 64 + (t & 7) * 8;
  const bf16* vp = Vt + ((long)bh * 64 + (t >> 2)) * 4096 + (t & 3) * 8;
  bf16* sKp = &sK[t * 8];
  bf16* sVp = &sV[t * 8];

  __syncthreads();   // sBias ready

  for (int kc = 0; kc < 4096; kc += 32) {
    short8 kv = *(const short8*)(kp + (long)kc * 64);
    short8 vv = *(const short8*)(vp + kc);
    *(short8*)sKp = kv;
    *(short8*)sVp = vv;
    __syncthreads();

    short8 k0a = *(const short8*)&sK[lr * 64 + quad * 8];
    short8 k0b = *(const short8*)&sK[lr * 64 + 32 + quad * 8];
    short8 k1a = *(const short8*)&sK[(16 + lr) * 64 + quad * 8];
    short8 k1b = *(const short8*)&sK[(16 + lr) * 64 + 32 + quad * 8];
    f32x4 s0 = {}, s1 = {};
    s0 = MFMA(q0, k0a, s0);
    s0 = MFMA(q1, k0b, s0);
    s1 = MFMA(q0, k1a, s1);
    s1 = MFMA(q1, k1b, s1);

    const float b0 = sBias[kc + lr], b1 = sBias[kc + 16 + lr];
#pragma unroll
    for (int r = 0; r < 4; r++) {
      float a0 = fmaf(s0[r], 0.125f, b0);      // /sqrt(64) + mask bias
      float a1 = fmaf(s1[r], 0.125f, b1);
      float mx = fmaxf(a0, a1);
#pragma unroll
      for (int off = 1; off < 16; off <<= 1) mx = fmaxf(mx, __shfl_xor(mx, off, 16));
      const float mnew = fmaxf(m_i[r], mx);
      const float p0 = __expf(a0 - mnew), p1 = __expf(a1 - mnew);
      float rs = p0 + p1;
#pragma unroll
      for (int off = 1; off < 16; off <<= 1) rs += __shfl_xor(rs, off, 16);
      const float sc = __expf(m_i[r] - mnew);  // exp(-inf)=0 on first chunk
      l_i[r] = l_i[r] * sc + rs;
      m_i[r] = mnew;
      O[0][r] *= sc; O[1][r] *= sc; O[2][r] *= sc; O[3][r] *= sc;
      sP[w][(quad * 4 + r) * 32 + lr]      = __float2bfloat16(p0);
      sP[w][(quad * 4 + r) * 32 + 16 + lr] = __float2bfloat16(p1);
    }
    __syncthreads();

    short8 pf = *(const short8*)&sP[w][lr * 32 + quad * 8];
#pragma unroll
    for (int j = 0; j < 4; j++) {
      short8 vf = *(const short8*)&sV[(j * 16 + lr) * 32 + quad * 8];
      O[j] = MFMA(pf, vf, O[j]);
    }
    __syncthreads();
  }

#pragma unroll
  for (int r = 0; r < 4; r++) {
    const float il = (l_i[r] > 0.f) ? 1.f / l_i[r] : 0.f;
    const int q = qb + quad * 4 + r;
    bf16* cp = ctx + ((long)(b * 4096 + q)) * 768 + hh * 64 + lr;
#pragma unroll
    for (int j = 0; j < 4; j++) cp[j * 16] = __float2bfloat16(O[j][r] * il);
  }
}

// ---------------------------------------------------------------------------
extern "C" void kernel_launch(void* const* d_in, const int* in_sizes, int n_in,
                              void* d_out, int out_size, void* d_ws, size_t ws_size,
                              hipStream_t stream)
{
  (void)in_sizes; (void)n_in; (void)out_size; (void)ws_size;
  const float* x    = (const float*)d_in[0];
  const int*   mask = (const int*)  d_in[1];
  const float* wq = (const float*)d_in[2];  const float* bq = (const float*)d_in[3];
  const float* wk = (const float*)d_in[4];  const float* bk = (const float*)d_in[5];
  const float* wv = (const float*)d_in[6];  const float* bv = (const float*)d_in[7];
  const float* wo = (const float*)d_in[8];  const float* bo = (const float*)d_in[9];
  const float* w1 = (const float*)d_in[10]; const float* b1 = (const float*)d_in[11];
  const float* w2 = (const float*)d_in[12]; const float* b2 = (const float*)d_in[13];
  const float* alpha1 = (const float*)d_in[14]; const float* beta1 = (const float*)d_in[15];
  const float* alpha2 = (const float*)d_in[16]; const float* beta2 = (const float*)d_in[17];
  float* out = (float*)d_out;

  // ---- workspace layout (bytes) ----
  // [0, 14.2MB): bf16 weight copies; [16MB, ...): activations
  const long WSZ = (long)768 * 768 * 2;        // 1,179,648
  const long W1SZ = (long)3072 * 768 * 2;      // 4,718,592
  const long SZB = (long)8192 * 768 * 2;       // 12,582,912
  char* ws = (char*)d_ws;
  bf16* wqb = (bf16*)(ws);
  bf16* wkb = (bf16*)(ws + 1 * WSZ);
  bf16* wvb = (bf16*)(ws + 2 * WSZ);
  bf16* wob = (bf16*)(ws + 3 * WSZ);
  bf16* w1b = (bf16*)(ws + 4 * WSZ);
  bf16* w2b = (bf16*)(ws + 4 * WSZ + W1SZ);
  const long BASE = 16l << 20;
  bf16* h   = (bf16*)(ws + BASE);            // LN output (reused as h2)
  bf16* qws = (bf16*)(ws + BASE + 1 * SZB);  // Q [B,H,S,64]
  bf16* kws = (bf16*)(ws + BASE + 2 * SZB);  // K [B,H,S,64]
  bf16* vtw = (bf16*)(ws + BASE + 3 * SZB);  // V^T [B,H,64,S]
  bf16* ctx = (bf16*)(ws + BASE + 4 * SZB);  // attention context [B,S,768]
  bf16* x1  = (bf16*)(ws + BASE + 5 * SZB);  // residual-1 output (bf16)
  bf16* ff  = qws;                           // FFN hidden [8192,3072] (48MB over q..ctx)
  // total ws use: 16MB + 6*SZB = 92.3 MB

  dim3 blk(256);
  dim3 g768(64, 6), g3072(64, 24);

  // weight conversions (same work every call; graph-safe)
  hipLaunchKernelGGL(conv_kernel, dim3(576),  blk, 0, stream, wq, wqb, 147456);
  hipLaunchKernelGGL(conv_kernel, dim3(576),  blk, 0, stream, wk, wkb, 147456);
  hipLaunchKernelGGL(conv_kernel, dim3(576),  blk, 0, stream, wv, wvb, 147456);
  hipLaunchKernelGGL(conv_kernel, dim3(576),  blk, 0, stream, wo, wob, 147456);
  hipLaunchKernelGGL(conv_kernel, dim3(2304), blk, 0, stream, w1, w1b, 589824);
  hipLaunchKernelGGL(conv_kernel, dim3(2304), blk, 0, stream, w2, w2b, 589824);

  hipLaunchKernelGGL((ln_kernel<float>), dim3(8192), blk, 0, stream, x, h, alpha1, beta1);
  hipLaunchKernelGGL((gemm_bt<2, float, bf16>), g768, blk, 0, stream, h, wqb, bq, (const float*)nullptr, qws, 8192, 768, 768);
  hipLaunchKernelGGL((gemm_bt<2, float, bf16>), g768, blk, 0, stream, h, wkb, bk, (const float*)nullptr, kws, 8192, 768, 768);
  hipLaunchKernelGGL((gemm_bt<3, float, bf16>), g768, blk, 0, stream, h, wvb, bv, (const float*)nullptr, vtw, 8192, 768, 768);
  hipLaunchKernelGGL(attn_kernel, dim3(64, 24), blk, 0, stream, qws, kws, vtw, mask, ctx);
  hipLaunchKernelGGL((gemm_bt<4, float, bf16>), g768, blk, 0, stream, ctx, wob, bo, x, x1, 8192, 768, 768);
  hipLaunchKernelGGL((ln_kernel<bf16>), dim3(8192), blk, 0, stream, x1, h, alpha2, beta2);
  hipLaunchKernelGGL((gemm_bt<1, float, bf16>), g3072, blk, 0, stream, h, w1b, b1, (const float*)nullptr, ff, 8192, 3072, 768);
  hipLaunchKernelGGL((gemm_bt<4, bf16, float>), g768, blk, 0, stream, ff, w2b, b2, x1, out, 8192, 768, 3072);
}

// Round 4
// 521.794 us; speedup vs baseline: 1.6906x; 1.6906x over previous
//
#include <hip/hip_runtime.h>
#include <hip/hip_bf16.h>
#include <math.h>

// EncoderBlock: B=2, S=4096, D_MODEL=768, H=12, dk=64, D_FF=3072.
// Inputs fp32 (mask int32), output fp32. Internal compute bf16 MFMA.
// Round 4: attention rewrite (Kc=64, 32q/wave, padded LDS, no-max softmax),
//          GEMM async global_load_lds staging (m97 form).

typedef __hip_bfloat16 bf16;
typedef short short8 __attribute__((ext_vector_type(8)));   // 8 bf16 (4 VGPRs)
typedef short short4v __attribute__((ext_vector_type(4)));  // 4 bf16 (8B)
typedef float f32x4 __attribute__((ext_vector_type(4)));

#define MFMA(A, B, C) __builtin_amdgcn_mfma_f32_16x16x32_bf16(A, B, C, 0, 0, 0)

__device__ __forceinline__ void gl_lds16(const void* g, void* l) {
  // async global->LDS, 16B/lane; LDS dest must be wave-uniform base + lane*16
  __builtin_amdgcn_global_load_lds(
      (__attribute__((address_space(1))) void*)g,
      (__attribute__((address_space(3))) void*)l, 16, 0, 0);
}

__device__ __forceinline__ short f2b(float f) {
  bf16 h = __float2bfloat16(f);
  return *reinterpret_cast<short*>(&h);
}

// ---------------- fp32 -> bf16 conversion (vectorized x4) -------------------
__global__ __launch_bounds__(256)
void conv_kernel(const float* __restrict__ src, bf16* __restrict__ dst, int n4)
{
  const int i = blockIdx.x * 256 + threadIdx.x;
  if (i < n4) {
    float4 v = ((const float4*)src)[i];
    short4v o;
    o.x = f2b(v.x); o.y = f2b(v.y); o.z = f2b(v.z); o.w = f2b(v.w);
    ((short4v*)dst)[i] = o;
  }
}

// ---------------- LayerNorm (scalar alpha/beta, unbiased std) ----------------
template<typename INT>
__global__ __launch_bounds__(256)
void ln_kernel(const INT* __restrict__ x, bf16* __restrict__ out,
               const float* __restrict__ alpha, const float* __restrict__ beta)
{
  const int row = blockIdx.x;
  const long base = (long)row * 768;
  const int t = threadIdx.x;
  float v[3]; float s = 0.f, ss = 0.f;
#pragma unroll
  for (int i = 0; i < 3; i++) {
    v[i] = (float)x[base + t + i * 256];
    s += v[i]; ss += v[i] * v[i];
  }
#pragma unroll
  for (int off = 32; off > 0; off >>= 1) {
    s  += __shfl_down(s, off);
    ss += __shfl_down(ss, off);
  }
  __shared__ float red[8];
  __shared__ float stats[2];
  const int w = t >> 6;
  if ((t & 63) == 0) { red[w] = s; red[4 + w] = ss; }
  __syncthreads();
  if (t == 0) {
    float S  = red[0] + red[1] + red[2] + red[3];
    float SS = red[4] + red[5] + red[6] + red[7];
    float mean = S * (1.f / 768.f);
    float var = fmaxf((SS - 768.f * mean * mean) * (1.f / 767.f), 0.f);
    stats[0] = mean;
    stats[1] = 1.f / (sqrtf(var) + 1e-6f);   // 1/(std+eps)
  }
  __syncthreads();
  const float mean = stats[0], rinv = stats[1];
  const float a = alpha[0], b = beta[0];
#pragma unroll
  for (int i = 0; i < 3; i++)
    out[base + t + i * 256] = __float2bfloat16(a * (v[i] - mean) * rinv + b);
}

// ---------------- GEMM: C[m][n] = sum_k A[m][k]*W[n][k] + bias[n] ------------
// MODE: 0 plain | 1 +ReLU | 2 scatter [B,H,S,dk] | 3 scatter [B,H,dk,S] (V^T)
//       4 +residual R[m][n]
template<int MODE, typename RT, typename OUTT>
__global__ __launch_bounds__(256)
void gemm_bt(const bf16* __restrict__ A, const bf16* __restrict__ W,
             const float* __restrict__ bias, const RT* __restrict__ R,
             OUTT* __restrict__ Cout, int M, int N, int K)
{
  __shared__ __align__(16) bf16 sA[128 * 32];
  __shared__ __align__(16) bf16 sB[128 * 32];
  const int t = threadIdx.x;
  const int w = t >> 6, lane = t & 63;
  const int lr = lane & 15, quad = lane >> 4;
  const int tm = blockIdx.x * 128, tn = blockIdx.y * 128;
  const int wm = (w >> 1) * 64, wn = (w & 1) * 64;

  // staging: thread t owns LDS bytes [t*16, t*16+16): wave-uniform base+lane*16
  const int srow = w * 16 + (lane >> 2);
  const int scol = (lane & 3) * 8;
  const bf16* Ap = A + (long)(tm + srow) * K + scol;
  const bf16* Wp = W + (long)(tn + srow) * K + scol;
  bf16* sAp = &sA[srow * 32 + scol];
  bf16* sBp = &sB[srow * 32 + scol];
  const long half = (long)64 * K;

  f32x4 acc[4][4] = {};

  for (int kb = 0; kb < K; kb += 32) {
    gl_lds16(Ap + kb, sAp);
    gl_lds16(Ap + kb + half, sAp + 64 * 32);
    gl_lds16(Wp + kb, sBp);
    gl_lds16(Wp + kb + half, sBp + 64 * 32);
    __syncthreads();                 // vmcnt(0) drain before LDS reads
    short8 af[4], bfr[4];
#pragma unroll
    for (int i = 0; i < 4; i++)
      af[i] = *(const short8*)&sA[(wm + i * 16 + lr) * 32 + quad * 8];
#pragma unroll
    for (int j = 0; j < 4; j++)
      bfr[j] = *(const short8*)&sB[(wn + j * 16 + lr) * 32 + quad * 8];
#pragma unroll
    for (int i = 0; i < 4; i++)
#pragma unroll
      for (int j = 0; j < 4; j++)
        acc[i][j] = MFMA(af[i], bfr[j], acc[i][j]);
    __syncthreads();
  }

#pragma unroll
  for (int i = 0; i < 4; i++) {
#pragma unroll
    for (int j = 0; j < 4; j++) {
      const int col = tn + wn + j * 16 + lr;
      const float bv = bias[col];
#pragma unroll
      for (int r = 0; r < 4; r++) {
        const int m = tm + wm + i * 16 + quad * 4 + r;
        float vv = acc[i][j][r] + bv;
        if (MODE == 1) vv = fmaxf(vv, 0.f);
        if (MODE == 4) vv += (float)R[(long)m * N + col];
        long oidx;
        if (MODE == 2) {
          const int hh = col >> 6, d = col & 63, bb = m >> 12, sdx = m & 4095;
          oidx = ((long)(bb * 12 + hh) * 4096 + sdx) * 64 + d;
        } else if (MODE == 3) {
          const int hh = col >> 6, d = col & 63, bb = m >> 12, sdx = m & 4095;
          oidx = ((long)(bb * 12 + hh) * 64 + d) * 4096 + sdx;
        } else {
          oidx = (long)m * N + col;
        }
        Cout[oidx] = (OUTT)vv;   // bf16: RNE convert; float: exact
      }
    }
  }
}

// ---------------- Flash attention (bounded-score softmax, no running max) ----
// Q,K: [B,H,S,64]; Vt: [B,H,64,S]; ctx out: [B,S,768] (all bf16)
// Block: 4 waves x 32 queries = 128 q. Chunk: 64 keys. Grid (32, 24).
// Scores = (q.k)/8 with unit-scale normed activations -> |s| << 80, so
// p = exp(s + maskbias) cannot overflow; l-reduction deferred to epilogue.
__global__ __launch_bounds__(256)
void attn_kernel(const bf16* __restrict__ Q, const bf16* __restrict__ Kg,
                 const bf16* __restrict__ Vt, const int* __restrict__ mask,
                 bf16* __restrict__ ctx)
{
  __shared__ __align__(16) bf16 sK[64 * 72];      // [key][d], stride 72: 2-way banks
  __shared__ __align__(16) bf16 sV[64 * 72];      // [d][key], stride 72
  __shared__ __align__(16) bf16 sP[4][32 * 72];   // per-wave P [q][key], stride 72
  __shared__ float sBias[4096];

  const int t = threadIdx.x, w = t >> 6, lane = t & 63;
  const int lr = lane & 15, quad = lane >> 4;
  const int bh = blockIdx.y, b = bh / 12, hh = bh % 12;
  const int qb = blockIdx.x * 128 + w * 32;       // this wave's 32 queries
  const long bh_s = (long)bh * 4096;

  for (int i = t; i < 4096; i += 256)
    sBias[i] = mask[b * 4096 + i] ? 0.f : -1e9f;

  // Q fragments (A-layout): lane holds Q[q=16qt+lr][d=quad*8+j], halves d<32/d>=32
  short8 qf[2][2];
#pragma unroll
  for (int qt = 0; qt < 2; qt++) {
    const bf16* qp = Q + (bh_s + qb + qt * 16 + lr) * 64 + quad * 8;
    qf[qt][0] = *(const short8*)qp;
    qf[qt][1] = *(const short8*)(qp + 32);
  }

  float l_part[2][4] = {};
  f32x4 O[2][4] = {};

  // staging: thread t owns key-rows {t>>3, 32+(t>>3)} x 8 cols of d (and V rows)
  const int srow = t >> 3;          // 0..31
  const int scol = (t & 7) * 8;     // 0..56
  const bf16* kp0 = Kg + (bh_s + srow) * 64 + scol;
  const bf16* kp1 = Kg + (bh_s + srow + 32) * 64 + scol;
  const bf16* vp0 = Vt + ((long)bh * 64 + srow) * 4096 + scol;
  const bf16* vp1 = Vt + ((long)bh * 64 + srow + 32) * 4096 + scol;

  __syncthreads();   // sBias ready

  for (int kc = 0; kc < 4096; kc += 64) {
    // global loads issue early (overlap previous chunk's compute)
    short8 k0 = *(const short8*)(kp0 + (long)kc * 64);
    short8 k1 = *(const short8*)(kp1 + (long)kc * 64);
    short8 v0 = *(const short8*)(vp0 + kc);
    short8 v1 = *(const short8*)(vp1 + kc);
    __syncthreads();   // previous chunk's LDS reads complete
    *(short8*)&sK[srow * 72 + scol]        = k0;
    *(short8*)&sK[(srow + 32) * 72 + scol] = k1;
    *(short8*)&sV[srow * 72 + scol]        = v0;
    *(short8*)&sV[(srow + 32) * 72 + scol] = v1;
    __syncthreads();   // staged data visible

    // ---- S = Q K^T : 2 qtiles x 4 ktiles x 2 d-halves = 16 MFMA ----
    f32x4 s[2][4] = {};
#pragma unroll
    for (int kt = 0; kt < 4; kt++) {
      short8 kfa = *(const short8*)&sK[(kt * 16 + lr) * 72 + quad * 8];
      short8 kfb = *(const short8*)&sK[(kt * 16 + lr) * 72 + 32 + quad * 8];
      s[0][kt] = MFMA(qf[0][0], kfa, s[0][kt]);
      s[0][kt] = MFMA(qf[0][1], kfb, s[0][kt]);
      s[1][kt] = MFMA(qf[1][0], kfa, s[1][kt]);
      s[1][kt] = MFMA(qf[1][1], kfb, s[1][kt]);
    }

    // ---- p = exp(s/8 + bias); accumulate per-lane l; P -> wave-private LDS ----
#pragma unroll
    for (int kt = 0; kt < 4; kt++) {
      const float bb = sBias[kc + kt * 16 + lr];
#pragma unroll
      for (int qt = 0; qt < 2; qt++) {
#pragma unroll
        for (int r = 0; r < 4; r++) {
          const float p = __expf(fmaf(s[qt][kt][r], 0.125f, bb));
          l_part[qt][r] += p;
          sP[w][(qt * 16 + quad * 4 + r) * 72 + kt * 16 + lr] = __float2bfloat16(p);
        }
      }
    }
    // wave-private sP: lgkmcnt ordering only, no barrier needed

    // ---- O += P V : 2 qtiles x 4 d-blocks x 2 k-halves = 16 MFMA ----
    short8 pf[2][2];
#pragma unroll
    for (int qt = 0; qt < 2; qt++) {
      pf[qt][0] = *(const short8*)&sP[w][(qt * 16 + lr) * 72 + quad * 8];
      pf[qt][1] = *(const short8*)&sP[w][(qt * 16 + lr) * 72 + 32 + quad * 8];
    }
#pragma unroll
    for (int j = 0; j < 4; j++) {
      short8 vfa = *(const short8*)&sV[(j * 16 + lr) * 72 + quad * 8];
      short8 vfb = *(const short8*)&sV[(j * 16 + lr) * 72 + 32 + quad * 8];
      O[0][j] = MFMA(pf[0][0], vfa, O[0][j]);
      O[0][j] = MFMA(pf[0][1], vfb, O[0][j]);
      O[1][j] = MFMA(pf[1][0], vfa, O[1][j]);
      O[1][j] = MFMA(pf[1][1], vfb, O[1][j]);
    }
  }

  // epilogue: reduce l over the 16 lr-lanes (one shuffle tree, once)
#pragma unroll
  for (int qt = 0; qt < 2; qt++) {
#pragma unroll
    for (int r = 0; r < 4; r++) {
      float l = l_part[qt][r];
#pragma unroll
      for (int off = 1; off < 16; off <<= 1) l += __shfl_xor(l, off, 16);
      const float il = (l > 0.f) ? 1.f / l : 0.f;
      const int q = qb + qt * 16 + quad * 4 + r;
      bf16* cp = ctx + ((long)(b * 4096 + q)) * 768 + hh * 64 + lr;
#pragma unroll
      for (int j = 0; j < 4; j++)
        cp[j * 16] = __float2bfloat16(O[qt][j][r] * il);
    }
  }
}

// ---------------------------------------------------------------------------
extern "C" void kernel_launch(void* const* d_in, const int* in_sizes, int n_in,
                              void* d_out, int out_size, void* d_ws, size_t ws_size,
                              hipStream_t stream)
{
  (void)in_sizes; (void)n_in; (void)out_size; (void)ws_size;
  const float* x    = (const float*)d_in[0];
  const int*   mask = (const int*)  d_in[1];
  const float* wq = (const float*)d_in[2];  const float* bq = (const float*)d_in[3];
  const float* wk = (const float*)d_in[4];  const float* bk = (const float*)d_in[5];
  const float* wv = (const float*)d_in[6];  const float* bv = (const float*)d_in[7];
  const float* wo = (const float*)d_in[8];  const float* bo = (const float*)d_in[9];
  const float* w1 = (const float*)d_in[10]; const float* b1 = (const float*)d_in[11];
  const float* w2 = (const float*)d_in[12]; const float* b2 = (const float*)d_in[13];
  const float* alpha1 = (const float*)d_in[14]; const float* beta1 = (const float*)d_in[15];
  const float* alpha2 = (const float*)d_in[16]; const float* beta2 = (const float*)d_in[17];
  float* out = (float*)d_out;

  // ---- workspace layout (bytes) ----
  const long WSZ = (long)768 * 768 * 2;        // 1,179,648
  const long W1SZ = (long)3072 * 768 * 2;      // 4,718,592
  const long SZB = (long)8192 * 768 * 2;       // 12,582,912
  char* ws = (char*)d_ws;
  bf16* wqb = (bf16*)(ws);
  bf16* wkb = (bf16*)(ws + 1 * WSZ);
  bf16* wvb = (bf16*)(ws + 2 * WSZ);
  bf16* wob = (bf16*)(ws + 3 * WSZ);
  bf16* w1b = (bf16*)(ws + 4 * WSZ);
  bf16* w2b = (bf16*)(ws + 4 * WSZ + W1SZ);
  const long BASE = 16l << 20;
  bf16* h   = (bf16*)(ws + BASE);            // LN output (reused as h2)
  bf16* qws = (bf16*)(ws + BASE + 1 * SZB);  // Q [B,H,S,64]
  bf16* kws = (bf16*)(ws + BASE + 2 * SZB);  // K [B,H,S,64]
  bf16* vtw = (bf16*)(ws + BASE + 3 * SZB);  // V^T [B,H,64,S]
  bf16* ctx = (bf16*)(ws + BASE + 4 * SZB);  // attention context [B,S,768]
  bf16* x1  = (bf16*)(ws + BASE + 5 * SZB);  // residual-1 output (bf16)
  bf16* ff  = qws;                           // FFN hidden [8192,3072]

  dim3 blk(256);
  dim3 g768(64, 6), g3072(64, 24);

  hipLaunchKernelGGL(conv_kernel, dim3(576),  blk, 0, stream, wq, wqb, 147456);
  hipLaunchKernelGGL(conv_kernel, dim3(576),  blk, 0, stream, wk, wkb, 147456);
  hipLaunchKernelGGL(conv_kernel, dim3(576),  blk, 0, stream, wv, wvb, 147456);
  hipLaunchKernelGGL(conv_kernel, dim3(576),  blk, 0, stream, wo, wob, 147456);
  hipLaunchKernelGGL(conv_kernel, dim3(2304), blk, 0, stream, w1, w1b, 589824);
  hipLaunchKernelGGL(conv_kernel, dim3(2304), blk, 0, stream, w2, w2b, 589824);

  hipLaunchKernelGGL((ln_kernel<float>), dim3(8192), blk, 0, stream, x, h, alpha1, beta1);
  hipLaunchKernelGGL((gemm_bt<2, float, bf16>), g768, blk, 0, stream, h, wqb, bq, (const float*)nullptr, qws, 8192, 768, 768);
  hipLaunchKernelGGL((gemm_bt<2, float, bf16>), g768, blk, 0, stream, h, wkb, bk, (const float*)nullptr, kws, 8192, 768, 768);
  hipLaunchKernelGGL((gemm_bt<3, float, bf16>), g768, blk, 0, stream, h, wvb, bv, (const float*)nullptr, vtw, 8192, 768, 768);
  hipLaunchKernelGGL(attn_kernel, dim3(32, 24), blk, 0, stream, qws, kws, vtw, mask, ctx);
  hipLaunchKernelGGL((gemm_bt<4, float, bf16>), g768, blk, 0, stream, ctx, wob, bo, x, x1, 8192, 768, 768);
  hipLaunchKernelGGL((ln_kernel<bf16>), dim3(8192), blk, 0, stream, x1, h, alpha2, beta2);
  hipLaunchKernelGGL((gemm_bt<1, float, bf16>), g3072, blk, 0, stream, h, w1b, b1, (const float*)nullptr, ff, 8192, 3072, 768);
  hipLaunchKernelGGL((gemm_bt<4, bf16, float>), g768, blk, 0, stream, ff, w2b, b2, x1, out, 8192, 768, 3072);
}